// Round 14
// baseline (155.093 us; speedup 1.0000x reference)
//
#include <hip/hip_runtime.h>
#include <math.h>

#define K 32
#define F 128
#define H 256
#define TAB 4096
#define QB 8
#define BMAX 16
#define RCUT2 100.0f
#define KBINS 64
#define BINCAP 2560
#define BCAP 128
#define FP 132   // padded LDS row stride
#define FRR 32   // rows per block in feat GEMM
#define WRR 16   // rows per block in wtab
#define NCELL 32768   // 8 batches x 4096 morton cells

__device__ __forceinline__ float ssp(float x) {
    return fmaxf(x, 0.0f) + log1pf(expf(-fabsf(x))) - 0.69314718055994531f;
}

__device__ __forceinline__ float d2f4(float4 p, float qx, float qy, float qz) {
    float dx = qx - p.x;
    float dy = qy - p.y;
    float dz = qz - p.z;
    return fmaf(dz, dz, fmaf(dy, dy, dx * dx));
}

__device__ __forceinline__ unsigned ebits4(unsigned v) {
    // spread 4 bits: b3 b2 b1 b0 -> b3 0 0 b2 0 0 b1 0 0 b0
    return (v & 1u) | ((v & 2u) << 2) | ((v & 4u) << 4) | ((v & 8u) << 6);
}

// ---------------- prep: seg boundaries + pos padding + query keys + hist zero ----------------
__global__ __launch_bounds__(256) void prep_kernel(const int* __restrict__ bc, int Nc,
                                                   int* __restrict__ ctx_start,
                                                   const float* __restrict__ posc,
                                                   float4* __restrict__ posc4,
                                                   const float* __restrict__ posq,
                                                   const int* __restrict__ bq,
                                                   int* __restrict__ qkey,
                                                   int* __restrict__ ghist,
                                                   int Nq, int padB, int qkB) {
    int blk = blockIdx.x;
    int tid = threadIdx.x;
    if (blk == 0) {
        if (tid <= BMAX) {
            int b = tid;
            int lo = 0, hi = Nc;
            while (lo < hi) {
                int mid = (lo + hi) >> 1;
                if (bc[mid] < b) lo = mid + 1; else hi = mid;
            }
            ctx_start[b] = lo;
        }
    } else if (blk <= padB) {
        int i = (blk - 1) * 256 + tid;
        if (i < Nc)
            posc4[i] = make_float4(posc[i * 3 + 0], posc[i * 3 + 1], posc[i * 3 + 2], 0.0f);
    } else if (blk <= padB + qkB) {
        int q = (blk - 1 - padB) * 256 + tid;
        if (q < Nq) {
            float px = posq[q * 3 + 0], py = posq[q * 3 + 1], pz = posq[q * 3 + 2];
            int xi = min(15, max(0, (int)(px * 0.8f)));
            int yi = min(15, max(0, (int)(py * 0.8f)));
            int zi = min(15, max(0, (int)(pz * 0.8f)));
            unsigned m = ebits4((unsigned)xi) | (ebits4((unsigned)yi) << 1) | (ebits4((unsigned)zi) << 2);
            qkey[q] = (bq[q] << 12) | (int)m;
        }
    } else {
        int i = (blk - 1 - padB - qkB) * 256 + tid;
        if (i < NCELL) ghist[i] = 0;
    }
}

// ---------------- histogram of query keys ----------------
__global__ __launch_bounds__(256) void qhist_kernel(const int* __restrict__ qkey,
                                                    int* __restrict__ ghist, int Nq) {
    int q = blockIdx.x * 256 + threadIdx.x;
    if (q < Nq) atomicAdd(&ghist[qkey[q]], 1);
}

// ---------------- exclusive scan of 32768 buckets (1 block) ----------------
__global__ __launch_bounds__(256) void qscan_kernel(int* __restrict__ ghist) {
    __shared__ int part[256];
    __shared__ int base[256];
    int tid = threadIdx.x;
    const int CH = NCELL / 256;   // 128
    int s = 0;
    for (int i = 0; i < CH; ++i) s += ghist[tid * CH + i];
    part[tid] = s;
    __syncthreads();
    if (tid == 0) {
        int run = 0;
        for (int i = 0; i < 256; ++i) { base[i] = run; run += part[i]; }
    }
    __syncthreads();
    int run = base[tid];
    for (int i = 0; i < CH; ++i) {
        int v = ghist[tid * CH + i];
        ghist[tid * CH + i] = run;
        run += v;
    }
}

// ---------------- scatter: qperm[rank] = q ----------------
__global__ __launch_bounds__(256) void qscatter_kernel(const int* __restrict__ qkey,
                                                       int* __restrict__ ghist,
                                                       int* __restrict__ qperm, int Nq) {
    int q = blockIdx.x * 256 + threadIdx.x;
    if (q < Nq) {
        int pos = atomicAdd(&ghist[qkey[q]], 1);
        qperm[pos] = q;
    }
}

// ---------------- feat: 8 rows x 2 cols per thread, FRR=32 ----------------
__global__ __launch_bounds__(256) void feat_kernel(const float* __restrict__ attr,
                                                   const float* __restrict__ lin1_w,
                                                   float* __restrict__ ctx_feat, int Nc) {
    __shared__ float sa[FRR][H];   // 32 KB
    int blk = blockIdx.x;
    int tid = threadIdx.x;
    int r0 = blk * FRR;
    int f = tid & 63;
    int g = tid >> 6;

    {
        float4* dst = (float4*)sa;
        const int total = FRR * H / 4;
        if (r0 + FRR <= Nc) {
            const float4* src = (const float4*)(attr + (size_t)r0 * H);
            for (int i = tid; i < total; i += 256) dst[i] = src[i];
        } else {
            for (int i = tid; i < total; i += 256) {
                int r = i / (H / 4);
                if (r0 + r < Nc) dst[i] = ((const float4*)(attr + (size_t)r0 * H))[i];
                else dst[i] = make_float4(0.0f, 0.0f, 0.0f, 0.0f);
            }
        }
    }
    __syncthreads();

    float acc0[8], acc1[8];
#pragma unroll
    for (int r = 0; r < 8; ++r) { acc0[r] = 0.0f; acc1[r] = 0.0f; }
    for (int k = 0; k < H; k += 4) {
        float wa0 = lin1_w[(k + 0) * F + f];
        float wa1 = lin1_w[(k + 1) * F + f];
        float wa2 = lin1_w[(k + 2) * F + f];
        float wa3 = lin1_w[(k + 3) * F + f];
        float wb0 = lin1_w[(k + 0) * F + f + 64];
        float wb1 = lin1_w[(k + 1) * F + f + 64];
        float wb2 = lin1_w[(k + 2) * F + f + 64];
        float wb3 = lin1_w[(k + 3) * F + f + 64];
#pragma unroll
        for (int r = 0; r < 8; ++r) {
            float4 a4 = *(const float4*)&sa[g * 8 + r][k];
            acc0[r] = fmaf(a4.x, wa0, acc0[r]);
            acc0[r] = fmaf(a4.y, wa1, acc0[r]);
            acc0[r] = fmaf(a4.z, wa2, acc0[r]);
            acc0[r] = fmaf(a4.w, wa3, acc0[r]);
            acc1[r] = fmaf(a4.x, wb0, acc1[r]);
            acc1[r] = fmaf(a4.y, wb1, acc1[r]);
            acc1[r] = fmaf(a4.z, wb2, acc1[r]);
            acc1[r] = fmaf(a4.w, wb3, acc1[r]);
        }
    }
#pragma unroll
    for (int r = 0; r < 8; ++r) {
        int row = r0 + g * 8 + r;
        if (row < Nc) {
            ctx_feat[(size_t)row * F + f] = acc0[r];
            ctx_feat[(size_t)row * F + f + 64] = acc1[r];
        }
    }
}

// ---------------- knn ----------------
__global__ __launch_bounds__(256) void knn_kernel(const float* __restrict__ posq,
                                                  const float4* __restrict__ posc4,
                                                  const int* __restrict__ bq,
                                                  const int* __restrict__ ctx_start,
                                                  int* __restrict__ nbr, int Nq) {
    __shared__ unsigned char sbin[4][BINCAP];
    __shared__ int hist[4][KBINS];
    __shared__ unsigned bkey[4][BCAP];
    __shared__ int bidx[4][BCAP];
    __shared__ int s_nwin[4], s_nbnd[4];

    int tid = threadIdx.x;
    int lane = tid & 63;
    int w = tid >> 6;
    int q = blockIdx.x * 4 + w;
    bool active = q < Nq;
    int qc = active ? q : 0;

    hist[w][lane] = 0;
    if (lane == 0) { s_nwin[w] = 0; s_nbnd[w] = 0; }

    float qx = posq[qc * 3 + 0];
    float qy = posq[qc * 3 + 1];
    float qz = posq[qc * 3 + 2];
    int b = bq[qc];
    int c0 = ctx_start[b];
    int c1 = ctx_start[b + 1];
    int seg = active ? (c1 - c0) : 0;
    __syncthreads();

    const float SCALE = (float)KBINS / RCUT2;
    int farc = -1;

    for (int i = lane; i < seg; i += 64) {
        float d2 = d2f4(posc4[c0 + i], qx, qy, qz);
        int bin = 255;
        if (d2 < RCUT2) {
            bin = (int)(d2 * SCALE);
            atomicAdd(&hist[w][bin], 1);
        }
        if (i < BINCAP) sbin[w][i] = (unsigned char)bin;
    }
    __syncthreads();

    int h = hist[w][lane];
    int inc = h;
#pragma unroll
    for (int off = 1; off < 64; off <<= 1) {
        int v = __shfl_up(inc, off);
        if (lane >= off) inc += v;
    }
    unsigned long long bal = __ballot(inc >= K);
    int T, below;
    if (bal) {
        T = __ffsll(bal) - 1;
        below = __shfl(inc, T) - __shfl(h, T);
    } else {
        T = KBINS;
        below = __shfl(inc, 63);
    }

    for (int i = lane; i < seg; i += 64) {
        int c = c0 + i;
        int bin;
        if (i < BINCAP) bin = sbin[w][i];
        else {
            float d2 = d2f4(posc4[c], qx, qy, qz);
            bin = (d2 < RCUT2) ? (int)(d2 * SCALE) : 255;
        }
        if (bin < T) {
            int p = atomicAdd(&s_nwin[w], 1);
            nbr[(size_t)q * K + p] = c;
        } else if (bin == T) {
            int p = atomicAdd(&s_nbnd[w], 1);
            if (p < BCAP) {
                float d2 = d2f4(posc4[c], qx, qy, qz);
                bkey[w][p] = __float_as_uint(d2);
                bidx[w][p] = c;
            }
        } else if (bin == 255) {
            farc = c;
        }
    }
#pragma unroll
    for (int off = 1; off < 64; off <<= 1) farc = max(farc, __shfl_xor(farc, off));
    if (farc < 0) farc = c0;
    __syncthreads();

    if (!active) return;
    int nb = min(s_nbnd[w], BCAP);
    int m = K - s_nwin[w];
    for (int it = 0; it < m; ++it) {
        unsigned long long bestkey = 0xFFFFFFFFFFFFFFFFull;
        int bestp = -1;
        for (int p = lane; p < nb; p += 64) {
            unsigned kk = bkey[w][p];
            if (kk != 0xFFFFFFFFu) {
                unsigned long long pk = ((unsigned long long)kk << 32) | (unsigned)bidx[w][p];
                if (pk < bestkey) { bestkey = pk; bestp = p; }
            }
        }
#pragma unroll
        for (int off = 1; off < 64; off <<= 1) {
            unsigned long long ok = __shfl_xor(bestkey, off);
            int op = __shfl_xor(bestp, off);
            if (ok < bestkey) { bestkey = ok; bestp = op; }
        }
        if (lane == 0) {
            if (bestp >= 0 && bestkey != 0xFFFFFFFFFFFFFFFFull) {
                nbr[(size_t)q * K + below + it] = (int)(bestkey & 0xFFFFFFFFu);
                bkey[w][bestp] = 0xFFFFFFFFu;
            } else {
                nbr[(size_t)q * K + below + it] = farc;
            }
        }
        __asm__ volatile("" ::: "memory");
    }
}

// ---------------- wtab: float2 lerp table ----------------
__global__ __launch_bounds__(256) void wtab_kernel(const float* __restrict__ nn1_w,
                                                   const float* __restrict__ nn1_b,
                                                   const float* __restrict__ nn2_w,
                                                   const float* __restrict__ nn2_b,
                                                   float2* __restrict__ wt2) {
    __shared__ float sg[17][F];
    __shared__ float st[17][F];
    int t0 = blockIdx.x * WRR;
    int tid = threadIdx.x;
    int f = tid & (F - 1);
    int g = tid >> 7;

    const float delta = 10.0f / 127.0f;
    const float coeff = -0.5f / (delta * delta);
    float off = (float)f * delta;
    for (int r = g; r < 17; r += 2) {
        float dist = (float)(t0 + r) * (10.0f / (float)TAB);
        float d = dist - off;
        sg[r][f] = expf(coeff * d * d);
    }
    __syncthreads();

    float acc[9];
#pragma unroll
    for (int r = 0; r < 9; ++r) acc[r] = 0.0f;
    for (int j = 0; j < F; j += 4) {
        float w0 = nn1_w[(j + 0) * F + f];
        float w1 = nn1_w[(j + 1) * F + f];
        float w2 = nn1_w[(j + 2) * F + f];
        float w3 = nn1_w[(j + 3) * F + f];
#pragma unroll
        for (int r = 0; r < 9; ++r) {
            float4 a4 = *(const float4*)&sg[g * 8 + r][j];
            acc[r] = fmaf(a4.x, w0, acc[r]);
            acc[r] = fmaf(a4.y, w1, acc[r]);
            acc[r] = fmaf(a4.z, w2, acc[r]);
            acc[r] = fmaf(a4.w, w3, acc[r]);
        }
    }
    float b1 = nn1_b[f];
#pragma unroll
    for (int r = 0; r < 9; ++r) st[g * 8 + r][f] = ssp(acc[r] + b1);
    __syncthreads();

#pragma unroll
    for (int r = 0; r < 9; ++r) acc[r] = 0.0f;
    for (int j = 0; j < F; j += 4) {
        float w0 = nn2_w[(j + 0) * F + f];
        float w1 = nn2_w[(j + 1) * F + f];
        float w2 = nn2_w[(j + 2) * F + f];
        float w3 = nn2_w[(j + 3) * F + f];
#pragma unroll
        for (int r = 0; r < 9; ++r) {
            float4 a4 = *(const float4*)&st[g * 8 + r][j];
            acc[r] = fmaf(a4.x, w0, acc[r]);
            acc[r] = fmaf(a4.y, w1, acc[r]);
            acc[r] = fmaf(a4.z, w2, acc[r]);
            acc[r] = fmaf(a4.w, w3, acc[r]);
        }
    }
    float b2 = nn2_b[f];
#pragma unroll
    for (int i = 0; i < 8; ++i) {
        int t = t0 + g * 8 + i;
        wt2[(size_t)t * F + f] = make_float2(acc[i] + b2, acc[i + 1] + b2);
    }
}

// ================= fused agg + head: 256 threads, QH=4, qperm-sorted blocks =================
// region0 [0,8448): sedge(4096)+sa(4096)+ssc(32); sc1/sp1 alias after stage A.
// region1 [8448,12672): sy. region2 [12672,12704): sq (query ids, live到 tails).
__global__ __launch_bounds__(256) void agghead_kernel(const float* __restrict__ posq,
                                                      const float4* __restrict__ posc4,
                                                      const int* __restrict__ nbr,
                                                      const float* __restrict__ ctx_feat,
                                                      const float2* __restrict__ wt2,
                                                      const int* __restrict__ qperm,
                                                      const float* __restrict__ lin2_w,
                                                      const float* __restrict__ lin2_b,
                                                      const float* __restrict__ cls1_w,
                                                      const float* __restrict__ cls1_b,
                                                      const float* __restrict__ cls2_w,
                                                      const float* __restrict__ cls2_b,
                                                      const float* __restrict__ prop1_w,
                                                      const float* __restrict__ prop1_b,
                                                      const float* __restrict__ prop2_w,
                                                      const float* __restrict__ prop2_b,
                                                      float* __restrict__ out_cls,
                                                      float* __restrict__ out_ind, int Nq) {
    const int QH = QB / 2;
    int q0 = blockIdx.x * QB;
    int tid = threadIdx.x;

    __shared__ __align__(16) char sm[12704];
    float4* sedge      = (float4*)sm;                       // [256]
    float (*sa)[F]     = (float (*)[F])(sm + 4096);         // [8][128]
    float* ssc         = (float*)(sm + 8192);               // [8]
    float (*sc1)[FP]   = (float (*)[FP])(sm);               // alias (after stage A)
    float (*sp1)[FP]   = (float (*)[FP])(sm + 4224);        // alias
    float (*sy)[FP]    = (float (*)[FP])(sm + 8448);        // [8][132]
    int* sq            = (int*)(sm + 12672);                // [8] actual query ids

    // ---- per-edge stage: one edge per thread (8q x 32k) ----
    {
        int qq = tid >> 5;
        int qi = q0 + qq;
        if (qi >= Nq) qi = Nq - 1;
        int q = qperm[qi];
        if ((tid & 31) == 0) sq[qq] = q;
        int j = nbr[(size_t)q * K + (tid & 31)];
        float4 p = posc4[j];
        float dx = posq[q * 3 + 0] - p.x;
        float dy = posq[q * 3 + 1] - p.y;
        float dz = posq[q * 3 + 2] - p.z;
        float dist = sqrtf(fmaf(dz, dz, fmaf(dy, dy, dx * dx)));
        float C = 0.0f, fr = 0.0f;
        int i0 = 0;
        if (dist <= 10.0f) {
            C = 0.5f * (cosf(dist * 0.31415926535897931f) + 1.0f);
            float u = dist * ((float)TAB / 10.0f);
            i0 = (int)u;
            if (i0 > TAB - 1) i0 = TAB - 1;
            fr = u - (float)i0;
        }
        sedge[tid] = make_float4(C, fr, __int_as_float(i0 * F), __int_as_float(j * F));
        float cs = C;
#pragma unroll
        for (int off = 1; off < 32; off <<= 1) cs += __shfl_xor(cs, off);
        if ((tid & 31) == 0) ssc[qq] = cs;
    }
    __syncthreads();

    int f = tid & (F - 1);
    int g = tid >> 7;

    // ---- agg ----
    {
        const float2* w2f = wt2 + f;
        const float* cff = ctx_feat + f;
        float acc[QH] = {0.0f, 0.0f, 0.0f, 0.0f};
#pragma unroll 2
        for (int k = 0; k < K; ++k) {
#pragma unroll
            for (int i = 0; i < QH; ++i) {
                float4 e4 = sedge[(g * QH + i) * K + k];
                float C = e4.x;
                float fr = e4.y;
                int i0f = __float_as_int(e4.z);
                int jf = __float_as_int(e4.w);
                float2 w = w2f[i0f];
                float a = cff[jf];
                float W = fmaf(fr, w.y - w.x, w.x);
                acc[i] = fmaf(C * W, a, acc[i]);
            }
        }
#pragma unroll
        for (int i = 0; i < QH; ++i) sa[g * QH + i][f] = acc[i];
    }
    __syncthreads();

    // ---- head stage A ----
    {
        float y[QH];
        float lb = lin2_b[f];
#pragma unroll
        for (int i = 0; i < QH; ++i) y[i] = ssc[g * QH + i] * lb;
        for (int j = 0; j < F; j += 4) {
            float w0 = lin2_w[(j + 0) * F + f];
            float w1 = lin2_w[(j + 1) * F + f];
            float w2 = lin2_w[(j + 2) * F + f];
            float w3 = lin2_w[(j + 3) * F + f];
#pragma unroll
            for (int i = 0; i < QH; ++i) {
                float4 a4 = *(const float4*)&sa[g * QH + i][j];
                y[i] = fmaf(a4.x, w0, y[i]);
                y[i] = fmaf(a4.y, w1, y[i]);
                y[i] = fmaf(a4.z, w2, y[i]);
                y[i] = fmaf(a4.w, w3, y[i]);
            }
        }
#pragma unroll
        for (int i = 0; i < QH; ++i) sy[g * QH + i][f] = y[i];
    }
    __syncthreads();   // sa/sedge/ssc dead; sc1/sp1 may overwrite

    // ---- head stage B ----
    {
        float c1[QH], p1[QH];
        float cb = cls1_b[f], pb = prop1_b[f];
#pragma unroll
        for (int i = 0; i < QH; ++i) { c1[i] = cb; p1[i] = pb; }
        for (int j = 0; j < F; j += 4) {
            float wc0 = cls1_w[(j + 0) * F + f];
            float wc1 = cls1_w[(j + 1) * F + f];
            float wc2 = cls1_w[(j + 2) * F + f];
            float wc3 = cls1_w[(j + 3) * F + f];
            float wp0 = prop1_w[(j + 0) * F + f];
            float wp1 = prop1_w[(j + 1) * F + f];
            float wp2 = prop1_w[(j + 2) * F + f];
            float wp3 = prop1_w[(j + 3) * F + f];
#pragma unroll
            for (int i = 0; i < QH; ++i) {
                float4 y4 = *(const float4*)&sy[g * QH + i][j];
                c1[i] = fmaf(y4.x, wc0, c1[i]);
                c1[i] = fmaf(y4.y, wc1, c1[i]);
                c1[i] = fmaf(y4.z, wc2, c1[i]);
                c1[i] = fmaf(y4.w, wc3, c1[i]);
                p1[i] = fmaf(y4.x, wp0, p1[i]);
                p1[i] = fmaf(y4.y, wp1, p1[i]);
                p1[i] = fmaf(y4.z, wp2, p1[i]);
                p1[i] = fmaf(y4.w, wp3, p1[i]);
            }
        }
#pragma unroll
        for (int i = 0; i < QH; ++i) {
            sc1[g * QH + i][f] = ssp(c1[i]);
            sp1[g * QH + i][f] = ssp(p1[i]);
        }
    }
    __syncthreads();

    // ---- tails: 8 queries x 15 outputs ----
    {
        int qq = tid >> 5;
        int c = tid & 31;
        int qi = q0 + qq;
        if (qi < Nq && c < 15) {
            int q = sq[qq];
            if (c < 7) {
                float acc = cls2_b[c];
                for (int j = 0; j < F; ++j) acc = fmaf(sc1[qq][j], cls2_w[j * 7 + c], acc);
                out_cls[(size_t)q * 7 + c] = acc;
            } else {
                int cc = c - 7;
                float acc = prop2_b[cc];
                for (int j = 0; j < F; ++j) acc = fmaf(sp1[qq][j], prop2_w[j * 8 + cc], acc);
                out_ind[(size_t)q * 8 + cc] = acc;
            }
        }
    }
}

extern "C" void kernel_launch(void* const* d_in, const int* in_sizes, int n_in,
                              void* d_out, int out_size, void* d_ws, size_t ws_size,
                              hipStream_t stream) {
    const float* posq   = (const float*)d_in[0];
    const float* posc   = (const float*)d_in[1];
    const float* attr   = (const float*)d_in[2];
    const int*   bq     = (const int*)d_in[3];
    const int*   bc     = (const int*)d_in[4];
    const float* lin1_w = (const float*)d_in[5];
    const float* lin2_w = (const float*)d_in[6];
    const float* lin2_b = (const float*)d_in[7];
    const float* nn1_w  = (const float*)d_in[8];
    const float* nn1_b  = (const float*)d_in[9];
    const float* nn2_w  = (const float*)d_in[10];
    const float* nn2_b  = (const float*)d_in[11];
    const float* cls1_w = (const float*)d_in[12];
    const float* cls1_b = (const float*)d_in[13];
    const float* cls2_w = (const float*)d_in[14];
    const float* cls2_b = (const float*)d_in[15];
    const float* prop1_w = (const float*)d_in[16];
    const float* prop1_b = (const float*)d_in[17];
    const float* prop2_w = (const float*)d_in[18];
    const float* prop2_b = (const float*)d_in[19];
    (void)n_in; (void)out_size; (void)ws_size;

    int Nq = in_sizes[0] / 3;
    int Nc = in_sizes[1] / 3;

    char* ws = (char*)d_ws;
    size_t off = 0;
    auto alloc = [&](size_t bytes) {
        off = (off + 255) & ~(size_t)255;
        void* p = ws + off;
        off += bytes;
        return p;
    };
    int*    ctx_start = (int*)alloc((BMAX + 1) * sizeof(int));
    int*    nbr       = (int*)alloc((size_t)Nq * K * sizeof(int));
    float*  ctx_feat  = (float*)alloc((size_t)Nc * F * sizeof(float));
    float2* wt2       = (float2*)alloc((size_t)TAB * F * sizeof(float2));
    float4* posc4     = (float4*)alloc((size_t)Nc * sizeof(float4));
    int*    qkey      = (int*)alloc((size_t)Nq * sizeof(int));
    int*    ghist     = (int*)alloc((size_t)NCELL * sizeof(int));
    int*    qperm     = (int*)alloc((size_t)Nq * sizeof(int));

    float* out_cls = (float*)d_out;
    float* out_ind = out_cls + (size_t)Nq * 7;

    int padB  = (Nc + 255) / 256;
    int qkB   = (Nq + 255) / 256;
    int zB    = (NCELL + 255) / 256;
    int featB = (Nc + FRR - 1) / FRR;
    int knnB  = (Nq + 3) / 4;
    int wtabB = TAB / WRR;

    prep_kernel<<<dim3(1 + padB + qkB + zB), dim3(256), 0, stream>>>(
        bc, Nc, ctx_start, posc, posc4, posq, bq, qkey, ghist, Nq, padB, qkB);
    qhist_kernel<<<dim3(qkB), dim3(256), 0, stream>>>(qkey, ghist, Nq);
    qscan_kernel<<<dim3(1), dim3(256), 0, stream>>>(ghist);
    qscatter_kernel<<<dim3(qkB), dim3(256), 0, stream>>>(qkey, ghist, qperm, Nq);
    knn_kernel<<<dim3(knnB), dim3(256), 0, stream>>>(posq, posc4, bq, ctx_start, nbr, Nq);
    feat_kernel<<<dim3(featB), dim3(256), 0, stream>>>(attr, lin1_w, ctx_feat, Nc);
    wtab_kernel<<<dim3(wtabB), dim3(256), 0, stream>>>(nn1_w, nn1_b, nn2_w, nn2_b, wt2);
    agghead_kernel<<<dim3((Nq + QB - 1) / QB), dim3(256), 0, stream>>>(
        posq, posc4, nbr, ctx_feat, wt2, qperm,
        lin2_w, lin2_b, cls1_w, cls1_b, cls2_w, cls2_b,
        prop1_w, prop1_b, prop2_w, prop2_b, out_cls, out_ind, Nq);
}

// Round 15
// 147.678 us; speedup vs baseline: 1.0502x; 1.0502x over previous
//
#include <hip/hip_runtime.h>
#include <math.h>

#define K 32
#define F 128
#define H 256
#define TAB 4096
#define QB 8
#define BMAX 16
#define RCUT2 100.0f
#define KBINS 64
#define BINCAP 2560
#define BCAP 128
#define FP 132   // padded LDS row stride
#define WRR 16   // rows per block in wtab
// feat GEMM tile
#define GM 128
#define GN 64
#define GK 32
#define GMP 132  // padded row stride of k-major A tile

__device__ __forceinline__ float ssp(float x) {
    return fmaxf(x, 0.0f) + log1pf(expf(-fabsf(x))) - 0.69314718055994531f;
}

__device__ __forceinline__ float d2f4(float4 p, float qx, float qy, float qz) {
    float dx = qx - p.x;
    float dy = qy - p.y;
    float dz = qz - p.z;
    return fmaf(dz, dz, fmaf(dy, dy, dx * dx));
}

// ---------------- prep: seg boundaries + pos padding ----------------
__global__ __launch_bounds__(256) void prep_kernel(const int* __restrict__ bc, int Nc,
                                                   int* __restrict__ ctx_start,
                                                   const float* __restrict__ posc,
                                                   float4* __restrict__ posc4) {
    int blk = blockIdx.x;
    int tid = threadIdx.x;
    if (blk == 0) {
        if (tid <= BMAX) {
            int b = tid;
            int lo = 0, hi = Nc;
            while (lo < hi) {
                int mid = (lo + hi) >> 1;
                if (bc[mid] < b) lo = mid + 1; else hi = mid;
            }
            ctx_start[b] = lo;
        }
    } else {
        int i = (blk - 1) * 256 + tid;
        if (i < Nc)
            posc4[i] = make_float4(posc[i * 3 + 0], posc[i * 3 + 1], posc[i * 3 + 2], 0.0f);
    }
}

// ---------------- feat: tiled GEMM, k-major LDS, 8x4 register tile ----------------
__global__ __launch_bounds__(256) void feat_kernel(const float* __restrict__ attr,
                                                   const float* __restrict__ lin1_w,
                                                   float* __restrict__ ctx_feat, int Nc) {
    __shared__ float At[GK][GMP];   // 16.9 KB, k-major (padded vs bank conflicts)
    __shared__ float Bt[GK][GN];    // 8 KB
    int tid = threadIdx.x;
    int r0 = blockIdx.x * GM;
    int n0 = blockIdx.y * GN;

    int tx = tid & 15;              // col group: n = n0 + tx*4
    int ty = tid >> 4;              // row group: m = ty*8

    float acc[8][4];
#pragma unroll
    for (int r = 0; r < 8; ++r)
#pragma unroll
        for (int c = 0; c < 4; ++c) acc[r][c] = 0.0f;

    for (int k0 = 0; k0 < H; k0 += GK) {
        // stage A: GM rows x GK k, transpose to k-major. 1024 float4s, 4/thread.
#pragma unroll
        for (int it = 0; it < 4; ++it) {
            int idx = tid + it * 256;
            int row = idx >> 3;
            int kc = (idx & 7) << 2;
            float4 v;
            if (r0 + row < Nc) v = *(const float4*)&attr[(size_t)(r0 + row) * H + k0 + kc];
            else v = make_float4(0.0f, 0.0f, 0.0f, 0.0f);
            At[kc + 0][row] = v.x;
            At[kc + 1][row] = v.y;
            At[kc + 2][row] = v.z;
            At[kc + 3][row] = v.w;
        }
        // stage B: GK x GN = 512 float4s, 2/thread.
#pragma unroll
        for (int it = 0; it < 2; ++it) {
            int idx = tid + it * 256;
            int kk = idx >> 4;
            int nc = (idx & 15) << 2;
            *(float4*)&Bt[kk][nc] = *(const float4*)&lin1_w[(size_t)(k0 + kk) * F + n0 + nc];
        }
        __syncthreads();

#pragma unroll 4
        for (int k = 0; k < GK; ++k) {
            float4 a0 = *(const float4*)&At[k][ty * 8];
            float4 a1 = *(const float4*)&At[k][ty * 8 + 4];
            float4 b4 = *(const float4*)&Bt[k][tx * 4];
            float av[8] = {a0.x, a0.y, a0.z, a0.w, a1.x, a1.y, a1.z, a1.w};
            float bv[4] = {b4.x, b4.y, b4.z, b4.w};
#pragma unroll
            for (int r = 0; r < 8; ++r)
#pragma unroll
                for (int c = 0; c < 4; ++c)
                    acc[r][c] = fmaf(av[r], bv[c], acc[r][c]);
        }
        __syncthreads();
    }

#pragma unroll
    for (int r = 0; r < 8; ++r) {
        int row = r0 + ty * 8 + r;
        if (row < Nc)
            *(float4*)&ctx_feat[(size_t)row * F + n0 + tx * 4] =
                make_float4(acc[r][0], acc[r][1], acc[r][2], acc[r][3]);
    }
}

// ---------------- knn ----------------
__global__ __launch_bounds__(256) void knn_kernel(const float* __restrict__ posq,
                                                  const float4* __restrict__ posc4,
                                                  const int* __restrict__ bq,
                                                  const int* __restrict__ ctx_start,
                                                  int* __restrict__ nbr, int Nq) {
    __shared__ unsigned char sbin[4][BINCAP];
    __shared__ int hist[4][KBINS];
    __shared__ unsigned bkey[4][BCAP];
    __shared__ int bidx[4][BCAP];
    __shared__ int s_nwin[4], s_nbnd[4];

    int tid = threadIdx.x;
    int lane = tid & 63;
    int w = tid >> 6;
    int q = blockIdx.x * 4 + w;
    bool active = q < Nq;
    int qc = active ? q : 0;

    hist[w][lane] = 0;
    if (lane == 0) { s_nwin[w] = 0; s_nbnd[w] = 0; }

    float qx = posq[qc * 3 + 0];
    float qy = posq[qc * 3 + 1];
    float qz = posq[qc * 3 + 2];
    int b = bq[qc];
    int c0 = ctx_start[b];
    int c1 = ctx_start[b + 1];
    int seg = active ? (c1 - c0) : 0;
    __syncthreads();

    const float SCALE = (float)KBINS / RCUT2;
    int farc = -1;

    for (int i = lane; i < seg; i += 64) {
        float d2 = d2f4(posc4[c0 + i], qx, qy, qz);
        int bin = 255;
        if (d2 < RCUT2) {
            bin = (int)(d2 * SCALE);
            atomicAdd(&hist[w][bin], 1);
        }
        if (i < BINCAP) sbin[w][i] = (unsigned char)bin;
    }
    __syncthreads();

    int h = hist[w][lane];
    int inc = h;
#pragma unroll
    for (int off = 1; off < 64; off <<= 1) {
        int v = __shfl_up(inc, off);
        if (lane >= off) inc += v;
    }
    unsigned long long bal = __ballot(inc >= K);
    int T, below;
    if (bal) {
        T = __ffsll(bal) - 1;
        below = __shfl(inc, T) - __shfl(h, T);
    } else {
        T = KBINS;
        below = __shfl(inc, 63);
    }

    for (int i = lane; i < seg; i += 64) {
        int c = c0 + i;
        int bin;
        if (i < BINCAP) bin = sbin[w][i];
        else {
            float d2 = d2f4(posc4[c], qx, qy, qz);
            bin = (d2 < RCUT2) ? (int)(d2 * SCALE) : 255;
        }
        if (bin < T) {
            int p = atomicAdd(&s_nwin[w], 1);
            nbr[(size_t)q * K + p] = c;
        } else if (bin == T) {
            int p = atomicAdd(&s_nbnd[w], 1);
            if (p < BCAP) {
                float d2 = d2f4(posc4[c], qx, qy, qz);
                bkey[w][p] = __float_as_uint(d2);
                bidx[w][p] = c;
            }
        } else if (bin == 255) {
            farc = c;
        }
    }
#pragma unroll
    for (int off = 1; off < 64; off <<= 1) farc = max(farc, __shfl_xor(farc, off));
    if (farc < 0) farc = c0;
    __syncthreads();

    if (!active) return;
    int nb = min(s_nbnd[w], BCAP);
    int m = K - s_nwin[w];
    // pick m smallest by (d2, ctx_index): deterministic under atomic reordering,
    // matches jax top_k stable lowest-index tie-break.
    for (int it = 0; it < m; ++it) {
        unsigned long long bestkey = 0xFFFFFFFFFFFFFFFFull;
        int bestp = -1;
        for (int p = lane; p < nb; p += 64) {
            unsigned kk = bkey[w][p];
            if (kk != 0xFFFFFFFFu) {
                unsigned long long pk = ((unsigned long long)kk << 32) | (unsigned)bidx[w][p];
                if (pk < bestkey) { bestkey = pk; bestp = p; }
            }
        }
#pragma unroll
        for (int off = 1; off < 64; off <<= 1) {
            unsigned long long ok = __shfl_xor(bestkey, off);
            int op = __shfl_xor(bestp, off);
            if (ok < bestkey) { bestkey = ok; bestp = op; }
        }
        if (lane == 0) {
            if (bestp >= 0 && bestkey != 0xFFFFFFFFFFFFFFFFull) {
                nbr[(size_t)q * K + below + it] = (int)(bestkey & 0xFFFFFFFFu);
                bkey[w][bestp] = 0xFFFFFFFFu;
            } else {
                nbr[(size_t)q * K + below + it] = farc;   // pad: contributes 0
            }
        }
        __asm__ volatile("" ::: "memory");
    }
}

// ---------------- wtab: float2 lerp table ----------------
__global__ __launch_bounds__(256) void wtab_kernel(const float* __restrict__ nn1_w,
                                                   const float* __restrict__ nn1_b,
                                                   const float* __restrict__ nn2_w,
                                                   const float* __restrict__ nn2_b,
                                                   float2* __restrict__ wt2) {
    __shared__ float sg[17][F];
    __shared__ float st[17][F];
    int t0 = blockIdx.x * WRR;
    int tid = threadIdx.x;
    int f = tid & (F - 1);
    int g = tid >> 7;

    const float delta = 10.0f / 127.0f;
    const float coeff = -0.5f / (delta * delta);
    float off = (float)f * delta;
    for (int r = g; r < 17; r += 2) {
        float dist = (float)(t0 + r) * (10.0f / (float)TAB);
        float d = dist - off;
        sg[r][f] = expf(coeff * d * d);
    }
    __syncthreads();

    float acc[9];
#pragma unroll
    for (int r = 0; r < 9; ++r) acc[r] = 0.0f;
    for (int j = 0; j < F; j += 4) {
        float w0 = nn1_w[(j + 0) * F + f];
        float w1 = nn1_w[(j + 1) * F + f];
        float w2 = nn1_w[(j + 2) * F + f];
        float w3 = nn1_w[(j + 3) * F + f];
#pragma unroll
        for (int r = 0; r < 9; ++r) {
            float4 a4 = *(const float4*)&sg[g * 8 + r][j];
            acc[r] = fmaf(a4.x, w0, acc[r]);
            acc[r] = fmaf(a4.y, w1, acc[r]);
            acc[r] = fmaf(a4.z, w2, acc[r]);
            acc[r] = fmaf(a4.w, w3, acc[r]);
        }
    }
    float b1 = nn1_b[f];
#pragma unroll
    for (int r = 0; r < 9; ++r) st[g * 8 + r][f] = ssp(acc[r] + b1);
    __syncthreads();

#pragma unroll
    for (int r = 0; r < 9; ++r) acc[r] = 0.0f;
    for (int j = 0; j < F; j += 4) {
        float w0 = nn2_w[(j + 0) * F + f];
        float w1 = nn2_w[(j + 1) * F + f];
        float w2 = nn2_w[(j + 2) * F + f];
        float w3 = nn2_w[(j + 3) * F + f];
#pragma unroll
        for (int r = 0; r < 9; ++r) {
            float4 a4 = *(const float4*)&st[g * 8 + r][j];
            acc[r] = fmaf(a4.x, w0, acc[r]);
            acc[r] = fmaf(a4.y, w1, acc[r]);
            acc[r] = fmaf(a4.z, w2, acc[r]);
            acc[r] = fmaf(a4.w, w3, acc[r]);
        }
    }
    float b2 = nn2_b[f];
#pragma unroll
    for (int i = 0; i < 8; ++i) {
        int t = t0 + g * 8 + i;
        wt2[(size_t)t * F + f] = make_float2(acc[i] + b2, acc[i + 1] + b2);
    }
}

// ================= fused agg + head: 256 threads, QH=4, LDS-aliased =================
__global__ __launch_bounds__(256) void agghead_kernel(const float* __restrict__ posq,
                                                      const float4* __restrict__ posc4,
                                                      const int* __restrict__ nbr,
                                                      const float* __restrict__ ctx_feat,
                                                      const float2* __restrict__ wt2,
                                                      const float* __restrict__ lin2_w,
                                                      const float* __restrict__ lin2_b,
                                                      const float* __restrict__ cls1_w,
                                                      const float* __restrict__ cls1_b,
                                                      const float* __restrict__ cls2_w,
                                                      const float* __restrict__ cls2_b,
                                                      const float* __restrict__ prop1_w,
                                                      const float* __restrict__ prop1_b,
                                                      const float* __restrict__ prop2_w,
                                                      const float* __restrict__ prop2_b,
                                                      float* __restrict__ out_cls,
                                                      float* __restrict__ out_ind, int Nq) {
    const int QH = QB / 2;
    int q0 = blockIdx.x * QB;
    int tid = threadIdx.x;

    __shared__ __align__(16) char sm[12672];
    float4* sedge      = (float4*)sm;                       // [256]
    float (*sa)[F]     = (float (*)[F])(sm + 4096);         // [8][128]
    float* ssc         = (float*)(sm + 8192);               // [8]
    float (*sc1)[FP]   = (float (*)[FP])(sm);               // alias (after stage A)
    float (*sp1)[FP]   = (float (*)[FP])(sm + 4224);        // alias
    float (*sy)[FP]    = (float (*)[FP])(sm + 8448);        // [8][132]

    // ---- per-edge stage ----
    {
        int qq = tid >> 5;
        int q = q0 + qq;
        if (q >= Nq) q = Nq - 1;
        int j = nbr[(size_t)q * K + (tid & 31)];
        float4 p = posc4[j];
        float dx = posq[q * 3 + 0] - p.x;
        float dy = posq[q * 3 + 1] - p.y;
        float dz = posq[q * 3 + 2] - p.z;
        float dist = sqrtf(fmaf(dz, dz, fmaf(dy, dy, dx * dx)));
        float C = 0.0f, fr = 0.0f;
        int i0 = 0;
        if (dist <= 10.0f) {
            C = 0.5f * (cosf(dist * 0.31415926535897931f) + 1.0f);
            float u = dist * ((float)TAB / 10.0f);
            i0 = (int)u;
            if (i0 > TAB - 1) i0 = TAB - 1;
            fr = u - (float)i0;
        }
        sedge[tid] = make_float4(C, fr, __int_as_float(i0 * F), __int_as_float(j * F));
        float cs = C;
#pragma unroll
        for (int off = 1; off < 32; off <<= 1) cs += __shfl_xor(cs, off);
        if ((tid & 31) == 0) ssc[qq] = cs;
    }
    __syncthreads();

    int f = tid & (F - 1);
    int g = tid >> 7;

    // ---- agg ----
    {
        const float2* w2f = wt2 + f;
        const float* cff = ctx_feat + f;
        float acc[QH] = {0.0f, 0.0f, 0.0f, 0.0f};
#pragma unroll 2
        for (int k = 0; k < K; ++k) {
#pragma unroll
            for (int i = 0; i < QH; ++i) {
                float4 e4 = sedge[(g * QH + i) * K + k];
                float C = e4.x;
                float fr = e4.y;
                int i0f = __float_as_int(e4.z);
                int jf = __float_as_int(e4.w);
                float2 w = w2f[i0f];
                float a = cff[jf];
                float W = fmaf(fr, w.y - w.x, w.x);
                acc[i] = fmaf(C * W, a, acc[i]);
            }
        }
#pragma unroll
        for (int i = 0; i < QH; ++i) sa[g * QH + i][f] = acc[i];
    }
    __syncthreads();

    // ---- head stage A ----
    {
        float y[QH];
        float lb = lin2_b[f];
#pragma unroll
        for (int i = 0; i < QH; ++i) y[i] = ssc[g * QH + i] * lb;
        for (int j = 0; j < F; j += 4) {
            float w0 = lin2_w[(j + 0) * F + f];
            float w1 = lin2_w[(j + 1) * F + f];
            float w2 = lin2_w[(j + 2) * F + f];
            float w3 = lin2_w[(j + 3) * F + f];
#pragma unroll
            for (int i = 0; i < QH; ++i) {
                float4 a4 = *(const float4*)&sa[g * QH + i][j];
                y[i] = fmaf(a4.x, w0, y[i]);
                y[i] = fmaf(a4.y, w1, y[i]);
                y[i] = fmaf(a4.z, w2, y[i]);
                y[i] = fmaf(a4.w, w3, y[i]);
            }
        }
#pragma unroll
        for (int i = 0; i < QH; ++i) sy[g * QH + i][f] = y[i];
    }
    __syncthreads();   // sa/sedge/ssc dead; sc1/sp1 may overwrite

    // ---- head stage B ----
    {
        float c1[QH], p1[QH];
        float cb = cls1_b[f], pb = prop1_b[f];
#pragma unroll
        for (int i = 0; i < QH; ++i) { c1[i] = cb; p1[i] = pb; }
        for (int j = 0; j < F; j += 4) {
            float wc0 = cls1_w[(j + 0) * F + f];
            float wc1 = cls1_w[(j + 1) * F + f];
            float wc2 = cls1_w[(j + 2) * F + f];
            float wc3 = cls1_w[(j + 3) * F + f];
            float wp0 = prop1_w[(j + 0) * F + f];
            float wp1 = prop1_w[(j + 1) * F + f];
            float wp2 = prop1_w[(j + 2) * F + f];
            float wp3 = prop1_w[(j + 3) * F + f];
#pragma unroll
            for (int i = 0; i < QH; ++i) {
                float4 y4 = *(const float4*)&sy[g * QH + i][j];
                c1[i] = fmaf(y4.x, wc0, c1[i]);
                c1[i] = fmaf(y4.y, wc1, c1[i]);
                c1[i] = fmaf(y4.z, wc2, c1[i]);
                c1[i] = fmaf(y4.w, wc3, c1[i]);
                p1[i] = fmaf(y4.x, wp0, p1[i]);
                p1[i] = fmaf(y4.y, wp1, p1[i]);
                p1[i] = fmaf(y4.z, wp2, p1[i]);
                p1[i] = fmaf(y4.w, wp3, p1[i]);
            }
        }
#pragma unroll
        for (int i = 0; i < QH; ++i) {
            sc1[g * QH + i][f] = ssp(c1[i]);
            sp1[g * QH + i][f] = ssp(p1[i]);
        }
    }
    __syncthreads();

    // ---- tails ----
    {
        int qq = tid >> 5;
        int c = tid & 31;
        int q = q0 + qq;
        if (q < Nq && c < 15) {
            if (c < 7) {
                float acc = cls2_b[c];
                for (int j = 0; j < F; ++j) acc = fmaf(sc1[qq][j], cls2_w[j * 7 + c], acc);
                out_cls[(size_t)q * 7 + c] = acc;
            } else {
                int cc = c - 7;
                float acc = prop2_b[cc];
                for (int j = 0; j < F; ++j) acc = fmaf(sp1[qq][j], prop2_w[j * 8 + cc], acc);
                out_ind[(size_t)q * 8 + cc] = acc;
            }
        }
    }
}

extern "C" void kernel_launch(void* const* d_in, const int* in_sizes, int n_in,
                              void* d_out, int out_size, void* d_ws, size_t ws_size,
                              hipStream_t stream) {
    const float* posq   = (const float*)d_in[0];
    const float* posc   = (const float*)d_in[1];
    const float* attr   = (const float*)d_in[2];
    const int*   bq     = (const int*)d_in[3];
    const int*   bc     = (const int*)d_in[4];
    const float* lin1_w = (const float*)d_in[5];
    const float* lin2_w = (const float*)d_in[6];
    const float* lin2_b = (const float*)d_in[7];
    const float* nn1_w  = (const float*)d_in[8];
    const float* nn1_b  = (const float*)d_in[9];
    const float* nn2_w  = (const float*)d_in[10];
    const float* nn2_b  = (const float*)d_in[11];
    const float* cls1_w = (const float*)d_in[12];
    const float* cls1_b = (const float*)d_in[13];
    const float* cls2_w = (const float*)d_in[14];
    const float* cls2_b = (const float*)d_in[15];
    const float* prop1_w = (const float*)d_in[16];
    const float* prop1_b = (const float*)d_in[17];
    const float* prop2_w = (const float*)d_in[18];
    const float* prop2_b = (const float*)d_in[19];
    (void)n_in; (void)out_size; (void)ws_size;

    int Nq = in_sizes[0] / 3;
    int Nc = in_sizes[1] / 3;

    char* ws = (char*)d_ws;
    size_t off = 0;
    auto alloc = [&](size_t bytes) {
        off = (off + 255) & ~(size_t)255;
        void* p = ws + off;
        off += bytes;
        return p;
    };
    int*    ctx_start = (int*)alloc((BMAX + 1) * sizeof(int));
    int*    nbr       = (int*)alloc((size_t)Nq * K * sizeof(int));
    float*  ctx_feat  = (float*)alloc((size_t)Nc * F * sizeof(float));
    float2* wt2       = (float2*)alloc((size_t)TAB * F * sizeof(float2));
    float4* posc4     = (float4*)alloc((size_t)Nc * sizeof(float4));

    float* out_cls = (float*)d_out;
    float* out_ind = out_cls + (size_t)Nq * 7;

    int padB  = (Nc + 255) / 256;
    int knnB  = (Nq + 3) / 4;
    int wtabB = TAB / WRR;
    int featBM = (Nc + GM - 1) / GM;
    int featBN = F / GN;

    prep_kernel<<<dim3(1 + padB), dim3(256), 0, stream>>>(bc, Nc, ctx_start, posc, posc4);
    knn_kernel<<<dim3(knnB), dim3(256), 0, stream>>>(posq, posc4, bq, ctx_start, nbr, Nq);
    feat_kernel<<<dim3(featBM, featBN), dim3(256), 0, stream>>>(attr, lin1_w, ctx_feat, Nc);
    wtab_kernel<<<dim3(wtabB), dim3(256), 0, stream>>>(nn1_w, nn1_b, nn2_w, nn2_b, wt2);
    agghead_kernel<<<dim3((Nq + QB - 1) / QB), dim3(256), 0, stream>>>(
        posq, posc4, nbr, ctx_feat, wt2,
        lin2_w, lin2_b, cls1_w, cls1_b, cls2_w, cls2_b,
        prop1_w, prop1_b, prop2_w, prop2_b, out_cls, out_ind, Nq);
}

// Round 16
// 136.650 us; speedup vs baseline: 1.1350x; 1.0807x over previous
//
#include <hip/hip_runtime.h>
#include <math.h>

#define K 32
#define F 128
#define H 256
#define TAB 4096
#define QB 8
#define BMAX 16
#define RCUT2 100.0f
#define KBINS 64
#define BINCAP 2560
#define BCAP 128
#define FP 132   // padded LDS row stride
#define FRR 32   // rows per block in feat GEMM
#define WRR 16   // rows per block in wtab

__device__ __forceinline__ float ssp(float x) {
    return fmaxf(x, 0.0f) + log1pf(expf(-fabsf(x))) - 0.69314718055994531f;
}

__device__ __forceinline__ float d2f4(float4 p, float qx, float qy, float qz) {
    float dx = qx - p.x;
    float dy = qy - p.y;
    float dz = qz - p.z;
    return fmaf(dz, dz, fmaf(dy, dy, dx * dx));
}

// ---------------- prep: seg boundaries + pos padding ----------------
__global__ __launch_bounds__(256) void prep_kernel(const int* __restrict__ bc, int Nc,
                                                   int* __restrict__ ctx_start,
                                                   const float* __restrict__ posc,
                                                   float4* __restrict__ posc4) {
    int blk = blockIdx.x;
    int tid = threadIdx.x;
    if (blk == 0) {
        if (tid <= BMAX) {
            int b = tid;
            int lo = 0, hi = Nc;
            while (lo < hi) {
                int mid = (lo + hi) >> 1;
                if (bc[mid] < b) lo = mid + 1; else hi = mid;
            }
            ctx_start[b] = lo;
        }
    } else {
        int i = (blk - 1) * 256 + tid;
        if (i < Nc)
            posc4[i] = make_float4(posc[i * 3 + 0], posc[i * 3 + 1], posc[i * 3 + 2], 0.0f);
    }
}

// ---------------- feat: 4 rows x 4 cols per thread, FRR=32, broadcast LDS ----------------
// per 4-k step: 4 ds_read_b128 + 16 coalesced weight loads + 64 FMA  (DS halved vs 8rx2c)
__global__ __launch_bounds__(256) void feat_kernel(const float* __restrict__ attr,
                                                   const float* __restrict__ lin1_w,
                                                   float* __restrict__ ctx_feat, int Nc) {
    __shared__ float sa[FRR][H];   // 32 KB
    int blk = blockIdx.x;
    int tid = threadIdx.x;
    int r0 = blk * FRR;
    int f = tid & 31;        // cols f + 32*c, c=0..3
    int g = tid >> 5;        // 8 row groups x 4 rows

    {
        float4* dst = (float4*)sa;
        const int total = FRR * H / 4;   // 2048
        if (r0 + FRR <= Nc) {
            const float4* src = (const float4*)(attr + (size_t)r0 * H);
            for (int i = tid; i < total; i += 256) dst[i] = src[i];
        } else {
            for (int i = tid; i < total; i += 256) {
                int r = i / (H / 4);
                if (r0 + r < Nc) dst[i] = ((const float4*)(attr + (size_t)r0 * H))[i];
                else dst[i] = make_float4(0.0f, 0.0f, 0.0f, 0.0f);
            }
        }
    }
    __syncthreads();

    float acc[4][4];
#pragma unroll
    for (int r = 0; r < 4; ++r)
#pragma unroll
        for (int c = 0; c < 4; ++c) acc[r][c] = 0.0f;

    for (int k = 0; k < H; k += 4) {
        float w[4][4];   // [kk][c]
#pragma unroll
        for (int kk = 0; kk < 4; ++kk)
#pragma unroll
            for (int c = 0; c < 4; ++c)
                w[kk][c] = lin1_w[(k + kk) * F + f + 32 * c];
#pragma unroll
        for (int r = 0; r < 4; ++r) {
            float4 a4 = *(const float4*)&sa[g * 4 + r][k];   // 2-addr broadcast (free)
#pragma unroll
            for (int c = 0; c < 4; ++c) {
                acc[r][c] = fmaf(a4.x, w[0][c], acc[r][c]);
                acc[r][c] = fmaf(a4.y, w[1][c], acc[r][c]);
                acc[r][c] = fmaf(a4.z, w[2][c], acc[r][c]);
                acc[r][c] = fmaf(a4.w, w[3][c], acc[r][c]);
            }
        }
    }
#pragma unroll
    for (int r = 0; r < 4; ++r) {
        int row = r0 + g * 4 + r;
        if (row < Nc) {
#pragma unroll
            for (int c = 0; c < 4; ++c)
                ctx_feat[(size_t)row * F + f + 32 * c] = acc[r][c];
        }
    }
}

// ---------------- knn ----------------
__global__ __launch_bounds__(256) void knn_kernel(const float* __restrict__ posq,
                                                  const float4* __restrict__ posc4,
                                                  const int* __restrict__ bq,
                                                  const int* __restrict__ ctx_start,
                                                  int* __restrict__ nbr, int Nq) {
    __shared__ unsigned char sbin[4][BINCAP];
    __shared__ int hist[4][KBINS];
    __shared__ unsigned bkey[4][BCAP];
    __shared__ int bidx[4][BCAP];
    __shared__ int s_nwin[4], s_nbnd[4];

    int tid = threadIdx.x;
    int lane = tid & 63;
    int w = tid >> 6;
    int q = blockIdx.x * 4 + w;
    bool active = q < Nq;
    int qc = active ? q : 0;

    hist[w][lane] = 0;
    if (lane == 0) { s_nwin[w] = 0; s_nbnd[w] = 0; }

    float qx = posq[qc * 3 + 0];
    float qy = posq[qc * 3 + 1];
    float qz = posq[qc * 3 + 2];
    int b = bq[qc];
    int c0 = ctx_start[b];
    int c1 = ctx_start[b + 1];
    int seg = active ? (c1 - c0) : 0;
    __syncthreads();

    const float SCALE = (float)KBINS / RCUT2;
    int farc = -1;

    for (int i = lane; i < seg; i += 64) {
        float d2 = d2f4(posc4[c0 + i], qx, qy, qz);
        int bin = 255;
        if (d2 < RCUT2) {
            bin = (int)(d2 * SCALE);
            atomicAdd(&hist[w][bin], 1);
        }
        if (i < BINCAP) sbin[w][i] = (unsigned char)bin;
    }
    __syncthreads();

    int h = hist[w][lane];
    int inc = h;
#pragma unroll
    for (int off = 1; off < 64; off <<= 1) {
        int v = __shfl_up(inc, off);
        if (lane >= off) inc += v;
    }
    unsigned long long bal = __ballot(inc >= K);
    int T, below;
    if (bal) {
        T = __ffsll(bal) - 1;
        below = __shfl(inc, T) - __shfl(h, T);
    } else {
        T = KBINS;
        below = __shfl(inc, 63);
    }

    for (int i = lane; i < seg; i += 64) {
        int c = c0 + i;
        int bin;
        if (i < BINCAP) bin = sbin[w][i];
        else {
            float d2 = d2f4(posc4[c], qx, qy, qz);
            bin = (d2 < RCUT2) ? (int)(d2 * SCALE) : 255;
        }
        if (bin < T) {
            int p = atomicAdd(&s_nwin[w], 1);
            nbr[(size_t)q * K + p] = c;
        } else if (bin == T) {
            int p = atomicAdd(&s_nbnd[w], 1);
            if (p < BCAP) {
                float d2 = d2f4(posc4[c], qx, qy, qz);
                bkey[w][p] = __float_as_uint(d2);
                bidx[w][p] = c;
            }
        } else if (bin == 255) {
            farc = c;
        }
    }
#pragma unroll
    for (int off = 1; off < 64; off <<= 1) farc = max(farc, __shfl_xor(farc, off));
    if (farc < 0) farc = c0;
    __syncthreads();

    if (!active) return;
    int nb = min(s_nbnd[w], BCAP);
    int m = K - s_nwin[w];
    // pick m smallest by (d2, ctx_index): deterministic under atomic reordering,
    // matches jax top_k stable lowest-index tie-break.
    for (int it = 0; it < m; ++it) {
        unsigned long long bestkey = 0xFFFFFFFFFFFFFFFFull;
        int bestp = -1;
        for (int p = lane; p < nb; p += 64) {
            unsigned kk = bkey[w][p];
            if (kk != 0xFFFFFFFFu) {
                unsigned long long pk = ((unsigned long long)kk << 32) | (unsigned)bidx[w][p];
                if (pk < bestkey) { bestkey = pk; bestp = p; }
            }
        }
#pragma unroll
        for (int off = 1; off < 64; off <<= 1) {
            unsigned long long ok = __shfl_xor(bestkey, off);
            int op = __shfl_xor(bestp, off);
            if (ok < bestkey) { bestkey = ok; bestp = op; }
        }
        if (lane == 0) {
            if (bestp >= 0 && bestkey != 0xFFFFFFFFFFFFFFFFull) {
                nbr[(size_t)q * K + below + it] = (int)(bestkey & 0xFFFFFFFFu);
                bkey[w][bestp] = 0xFFFFFFFFu;
            } else {
                nbr[(size_t)q * K + below + it] = farc;   // pad: contributes 0
            }
        }
        __asm__ volatile("" ::: "memory");
    }
}

// ---------------- wtab: float2 lerp table ----------------
__global__ __launch_bounds__(256) void wtab_kernel(const float* __restrict__ nn1_w,
                                                   const float* __restrict__ nn1_b,
                                                   const float* __restrict__ nn2_w,
                                                   const float* __restrict__ nn2_b,
                                                   float2* __restrict__ wt2) {
    __shared__ float sg[17][F];
    __shared__ float st[17][F];
    int t0 = blockIdx.x * WRR;
    int tid = threadIdx.x;
    int f = tid & (F - 1);
    int g = tid >> 7;

    const float delta = 10.0f / 127.0f;
    const float coeff = -0.5f / (delta * delta);
    float off = (float)f * delta;
    for (int r = g; r < 17; r += 2) {
        float dist = (float)(t0 + r) * (10.0f / (float)TAB);
        float d = dist - off;
        sg[r][f] = expf(coeff * d * d);
    }
    __syncthreads();

    float acc[9];
#pragma unroll
    for (int r = 0; r < 9; ++r) acc[r] = 0.0f;
    for (int j = 0; j < F; j += 4) {
        float w0 = nn1_w[(j + 0) * F + f];
        float w1 = nn1_w[(j + 1) * F + f];
        float w2 = nn1_w[(j + 2) * F + f];
        float w3 = nn1_w[(j + 3) * F + f];
#pragma unroll
        for (int r = 0; r < 9; ++r) {
            float4 a4 = *(const float4*)&sg[g * 8 + r][j];
            acc[r] = fmaf(a4.x, w0, acc[r]);
            acc[r] = fmaf(a4.y, w1, acc[r]);
            acc[r] = fmaf(a4.z, w2, acc[r]);
            acc[r] = fmaf(a4.w, w3, acc[r]);
        }
    }
    float b1 = nn1_b[f];
#pragma unroll
    for (int r = 0; r < 9; ++r) st[g * 8 + r][f] = ssp(acc[r] + b1);
    __syncthreads();

#pragma unroll
    for (int r = 0; r < 9; ++r) acc[r] = 0.0f;
    for (int j = 0; j < F; j += 4) {
        float w0 = nn2_w[(j + 0) * F + f];
        float w1 = nn2_w[(j + 1) * F + f];
        float w2 = nn2_w[(j + 2) * F + f];
        float w3 = nn2_w[(j + 3) * F + f];
#pragma unroll
        for (int r = 0; r < 9; ++r) {
            float4 a4 = *(const float4*)&st[g * 8 + r][j];
            acc[r] = fmaf(a4.x, w0, acc[r]);
            acc[r] = fmaf(a4.y, w1, acc[r]);
            acc[r] = fmaf(a4.z, w2, acc[r]);
            acc[r] = fmaf(a4.w, w3, acc[r]);
        }
    }
    float b2 = nn2_b[f];
#pragma unroll
    for (int i = 0; i < 8; ++i) {
        int t = t0 + g * 8 + i;
        wt2[(size_t)t * F + f] = make_float2(acc[i] + b2, acc[i + 1] + b2);
    }
}

// ================= fused agg + head: 256 threads, QH=4, LDS-aliased (R12 body) =================
__global__ __launch_bounds__(256) void agghead_kernel(const float* __restrict__ posq,
                                                      const float4* __restrict__ posc4,
                                                      const int* __restrict__ nbr,
                                                      const float* __restrict__ ctx_feat,
                                                      const float2* __restrict__ wt2,
                                                      const float* __restrict__ lin2_w,
                                                      const float* __restrict__ lin2_b,
                                                      const float* __restrict__ cls1_w,
                                                      const float* __restrict__ cls1_b,
                                                      const float* __restrict__ cls2_w,
                                                      const float* __restrict__ cls2_b,
                                                      const float* __restrict__ prop1_w,
                                                      const float* __restrict__ prop1_b,
                                                      const float* __restrict__ prop2_w,
                                                      const float* __restrict__ prop2_b,
                                                      float* __restrict__ out_cls,
                                                      float* __restrict__ out_ind, int Nq) {
    const int QH = QB / 2;
    int q0 = blockIdx.x * QB;
    int tid = threadIdx.x;

    __shared__ __align__(16) char sm[12672];
    float4* sedge      = (float4*)sm;                       // [256]
    float (*sa)[F]     = (float (*)[F])(sm + 4096);         // [8][128]
    float* ssc         = (float*)(sm + 8192);               // [8]
    float (*sc1)[FP]   = (float (*)[FP])(sm);               // alias (after stage A)
    float (*sp1)[FP]   = (float (*)[FP])(sm + 4224);        // alias
    float (*sy)[FP]    = (float (*)[FP])(sm + 8448);        // [8][132]

    // ---- per-edge stage ----
    {
        int qq = tid >> 5;
        int q = q0 + qq;
        if (q >= Nq) q = Nq - 1;
        int j = nbr[(size_t)q * K + (tid & 31)];
        float4 p = posc4[j];
        float dx = posq[q * 3 + 0] - p.x;
        float dy = posq[q * 3 + 1] - p.y;
        float dz = posq[q * 3 + 2] - p.z;
        float dist = sqrtf(fmaf(dz, dz, fmaf(dy, dy, dx * dx)));
        float C = 0.0f, fr = 0.0f;
        int i0 = 0;
        if (dist <= 10.0f) {
            C = 0.5f * (cosf(dist * 0.31415926535897931f) + 1.0f);
            float u = dist * ((float)TAB / 10.0f);
            i0 = (int)u;
            if (i0 > TAB - 1) i0 = TAB - 1;
            fr = u - (float)i0;
        }
        sedge[tid] = make_float4(C, fr, __int_as_float(i0 * F), __int_as_float(j * F));
        float cs = C;
#pragma unroll
        for (int off = 1; off < 32; off <<= 1) cs += __shfl_xor(cs, off);
        if ((tid & 31) == 0) ssc[qq] = cs;
    }
    __syncthreads();

    int f = tid & (F - 1);
    int g = tid >> 7;

    // ---- agg ----
    {
        const float2* w2f = wt2 + f;
        const float* cff = ctx_feat + f;
        float acc[QH] = {0.0f, 0.0f, 0.0f, 0.0f};
#pragma unroll 2
        for (int k = 0; k < K; ++k) {
#pragma unroll
            for (int i = 0; i < QH; ++i) {
                float4 e4 = sedge[(g * QH + i) * K + k];
                float C = e4.x;
                float fr = e4.y;
                int i0f = __float_as_int(e4.z);
                int jf = __float_as_int(e4.w);
                float2 w = w2f[i0f];
                float a = cff[jf];
                float W = fmaf(fr, w.y - w.x, w.x);
                acc[i] = fmaf(C * W, a, acc[i]);
            }
        }
#pragma unroll
        for (int i = 0; i < QH; ++i) sa[g * QH + i][f] = acc[i];
    }
    __syncthreads();

    // ---- head stage A ----
    {
        float y[QH];
        float lb = lin2_b[f];
#pragma unroll
        for (int i = 0; i < QH; ++i) y[i] = ssc[g * QH + i] * lb;
        for (int j = 0; j < F; j += 4) {
            float w0 = lin2_w[(j + 0) * F + f];
            float w1 = lin2_w[(j + 1) * F + f];
            float w2 = lin2_w[(j + 2) * F + f];
            float w3 = lin2_w[(j + 3) * F + f];
#pragma unroll
            for (int i = 0; i < QH; ++i) {
                float4 a4 = *(const float4*)&sa[g * QH + i][j];
                y[i] = fmaf(a4.x, w0, y[i]);
                y[i] = fmaf(a4.y, w1, y[i]);
                y[i] = fmaf(a4.z, w2, y[i]);
                y[i] = fmaf(a4.w, w3, y[i]);
            }
        }
#pragma unroll
        for (int i = 0; i < QH; ++i) sy[g * QH + i][f] = y[i];
    }
    __syncthreads();   // sa/sedge/ssc dead; sc1/sp1 may overwrite

    // ---- head stage B ----
    {
        float c1[QH], p1[QH];
        float cb = cls1_b[f], pb = prop1_b[f];
#pragma unroll
        for (int i = 0; i < QH; ++i) { c1[i] = cb; p1[i] = pb; }
        for (int j = 0; j < F; j += 4) {
            float wc0 = cls1_w[(j + 0) * F + f];
            float wc1 = cls1_w[(j + 1) * F + f];
            float wc2 = cls1_w[(j + 2) * F + f];
            float wc3 = cls1_w[(j + 3) * F + f];
            float wp0 = prop1_w[(j + 0) * F + f];
            float wp1 = prop1_w[(j + 1) * F + f];
            float wp2 = prop1_w[(j + 2) * F + f];
            float wp3 = prop1_w[(j + 3) * F + f];
#pragma unroll
            for (int i = 0; i < QH; ++i) {
                float4 y4 = *(const float4*)&sy[g * QH + i][j];
                c1[i] = fmaf(y4.x, wc0, c1[i]);
                c1[i] = fmaf(y4.y, wc1, c1[i]);
                c1[i] = fmaf(y4.z, wc2, c1[i]);
                c1[i] = fmaf(y4.w, wc3, c1[i]);
                p1[i] = fmaf(y4.x, wp0, p1[i]);
                p1[i] = fmaf(y4.y, wp1, p1[i]);
                p1[i] = fmaf(y4.z, wp2, p1[i]);
                p1[i] = fmaf(y4.w, wp3, p1[i]);
            }
        }
#pragma unroll
        for (int i = 0; i < QH; ++i) {
            sc1[g * QH + i][f] = ssp(c1[i]);
            sp1[g * QH + i][f] = ssp(p1[i]);
        }
    }
    __syncthreads();

    // ---- tails ----
    {
        int qq = tid >> 5;
        int c = tid & 31;
        int q = q0 + qq;
        if (q < Nq && c < 15) {
            if (c < 7) {
                float acc = cls2_b[c];
                for (int j = 0; j < F; ++j) acc = fmaf(sc1[qq][j], cls2_w[j * 7 + c], acc);
                out_cls[(size_t)q * 7 + c] = acc;
            } else {
                int cc = c - 7;
                float acc = prop2_b[cc];
                for (int j = 0; j < F; ++j) acc = fmaf(sp1[qq][j], prop2_w[j * 8 + cc], acc);
                out_ind[(size_t)q * 8 + cc] = acc;
            }
        }
    }
}

extern "C" void kernel_launch(void* const* d_in, const int* in_sizes, int n_in,
                              void* d_out, int out_size, void* d_ws, size_t ws_size,
                              hipStream_t stream) {
    const float* posq   = (const float*)d_in[0];
    const float* posc   = (const float*)d_in[1];
    const float* attr   = (const float*)d_in[2];
    const int*   bq     = (const int*)d_in[3];
    const int*   bc     = (const int*)d_in[4];
    const float* lin1_w = (const float*)d_in[5];
    const float* lin2_w = (const float*)d_in[6];
    const float* lin2_b = (const float*)d_in[7];
    const float* nn1_w  = (const float*)d_in[8];
    const float* nn1_b  = (const float*)d_in[9];
    const float* nn2_w  = (const float*)d_in[10];
    const float* nn2_b  = (const float*)d_in[11];
    const float* cls1_w = (const float*)d_in[12];
    const float* cls1_b = (const float*)d_in[13];
    const float* cls2_w = (const float*)d_in[14];
    const float* cls2_b = (const float*)d_in[15];
    const float* prop1_w = (const float*)d_in[16];
    const float* prop1_b = (const float*)d_in[17];
    const float* prop2_w = (const float*)d_in[18];
    const float* prop2_b = (const float*)d_in[19];
    (void)n_in; (void)out_size; (void)ws_size;

    int Nq = in_sizes[0] / 3;
    int Nc = in_sizes[1] / 3;

    char* ws = (char*)d_ws;
    size_t off = 0;
    auto alloc = [&](size_t bytes) {
        off = (off + 255) & ~(size_t)255;
        void* p = ws + off;
        off += bytes;
        return p;
    };
    int*    ctx_start = (int*)alloc((BMAX + 1) * sizeof(int));
    int*    nbr       = (int*)alloc((size_t)Nq * K * sizeof(int));
    float*  ctx_feat  = (float*)alloc((size_t)Nc * F * sizeof(float));
    float2* wt2       = (float2*)alloc((size_t)TAB * F * sizeof(float2));
    float4* posc4     = (float4*)alloc((size_t)Nc * sizeof(float4));

    float* out_cls = (float*)d_out;
    float* out_ind = out_cls + (size_t)Nq * 7;

    int padB  = (Nc + 255) / 256;
    int featB = (Nc + FRR - 1) / FRR;       // 512
    int knnB  = (Nq + 3) / 4;               // 2048
    int wtabB = TAB / WRR;                  // 256

    prep_kernel<<<dim3(1 + padB), dim3(256), 0, stream>>>(bc, Nc, ctx_start, posc, posc4);
    knn_kernel<<<dim3(knnB), dim3(256), 0, stream>>>(posq, posc4, bq, ctx_start, nbr, Nq);
    feat_kernel<<<dim3(featB), dim3(256), 0, stream>>>(attr, lin1_w, ctx_feat, Nc);
    wtab_kernel<<<dim3(wtabB), dim3(256), 0, stream>>>(nn1_w, nn1_b, nn2_w, nn2_b, wt2);
    agghead_kernel<<<dim3((Nq + QB - 1) / QB), dim3(256), 0, stream>>>(
        posq, posc4, nbr, ctx_feat, wt2,
        lin2_w, lin2_b, cls1_w, cls1_b, cls2_w, cls2_b,
        prop1_w, prop1_b, prop2_w, prop2_b, out_cls, out_ind, Nq);
}